// Round 14
// baseline (134.317 us; speedup 1.0000x reference)
//
#include <hip/hip_runtime.h>

typedef unsigned short ushort;
typedef short bf16x8 __attribute__((ext_vector_type(8)));   // 8 bf16 in 4 VGPRs
typedef float f32x4 __attribute__((ext_vector_type(4)));

static __device__ __forceinline__ ushort f2b(float f) {
  unsigned u = __builtin_bit_cast(unsigned, f);
  u = (u + 0x7fffu + ((u >> 16) & 1u)) >> 16;
  return (ushort)u;
}
static __device__ __forceinline__ float b2f(ushort b) {
  return __builtin_bit_cast(float, (unsigned)b << 16);
}

// ---------------------------------------------------------------------------
// prep: LDS-tiled 32x32 transpose for all five fp32->bf16 transposes.
// ---------------------------------------------------------------------------
__global__ __launch_bounds__(256) void prep_kernel(
    const float* __restrict__ x,
    const float* __restrict__ w_qkv, const float* __restrict__ w_proj,
    const float* __restrict__ w_fc1, const float* __restrict__ w_fc2,
    ushort* __restrict__ xb, ushort* __restrict__ wqkvT,
    ushort* __restrict__ wprojT, ushort* __restrict__ wfc1T,
    ushort* __restrict__ wfc2T)
{
  __shared__ float tile[32][33];
  int t = blockIdx.x;
  const float* src; ushort* dst; int R, Nc, r0, c0;
  if (t < 2048)              { src = x;      dst = xb;     R = 256; Nc = 8192; r0 = (t >> 8) * 32; c0 = (t & 255) * 32; }
  else if ((t -= 2048) < 192){ src = w_qkv;  dst = wqkvT;  R = 256; Nc = 768;  r0 = (t / 24) * 32; c0 = (t % 24) * 32; }
  else if ((t -= 192) < 64)  { src = w_proj; dst = wprojT; R = 256; Nc = 256;  r0 = (t / 8) * 32;  c0 = (t % 8) * 32; }
  else if ((t -= 64) < 128)  { src = w_fc1;  dst = wfc1T;  R = 256; Nc = 512;  r0 = (t / 16) * 32; c0 = (t % 16) * 32; }
  else           { t -= 128;   src = w_fc2;  dst = wfc2T;  R = 512; Nc = 256;  r0 = (t / 8) * 32;  c0 = (t % 8) * 32; }

  const int tx = threadIdx.x & 31, ty = threadIdx.x >> 5;
  #pragma unroll
  for (int i = 0; i < 4; i++)
    tile[ty + i * 8][tx] = src[(size_t)(r0 + ty + i * 8) * Nc + c0 + tx];
  __syncthreads();
  #pragma unroll
  for (int i = 0; i < 4; i++)
    dst[(size_t)(c0 + ty + i * 8) * R + r0 + tx] = f2b(tile[tx][ty + i * 8]);
}

// ---------------------------------------------------------------------------
// MFMA bf16 GEMM, 64x64 tile, 4 waves, BK=128 (round-11 engine).
// EPI 0: qkv -> q,k rows to C0[m*N+n]; v (n>=512) -> C1 vT[(n-512)*8192+m]
// EPI 2: fc1   -> gelu(v) -> bf16 C0[m*N+n]
// EPI 3: fc2   -> v += b2f(RS[m*256+n]); out[n*M+m]=v (f32 chw, float4)
// ---------------------------------------------------------------------------
template<int EPI, int KD>
__global__ __launch_bounds__(256) void gemm_mfma(
    const ushort* __restrict__ A, const ushort* __restrict__ Bt,
    const float* __restrict__ bias, const ushort* __restrict__ RS,
    void* __restrict__ C0, void* __restrict__ C1,
    int M, int N)
{
  constexpr int LDW = 136;                      // padded row stride (ushorts)
  __shared__ __attribute__((aligned(16))) ushort As[64 * LDW];
  __shared__ __attribute__((aligned(16))) ushort Bs[64 * LDW];

  const int bm = blockIdx.y * 64;
  const int bn = blockIdx.x * 64;
  const int t  = threadIdx.x;
  const int w    = t >> 6;
  const int lane = t & 63;
  const int wm = (w & 1) * 32;
  const int wn = (w >> 1) * 32;
  const int lm = lane & 15;
  const int kq = lane >> 4;                     // 0..3

  f32x4 acc[2][2] = {};

  #pragma unroll
  for (int k0 = 0; k0 < KD; k0 += 128) {
    uint4 ra[4], rb[4];
    #pragma unroll
    for (int s = 0; s < 4; s++) {
      const int L = t + 256 * s;
      const int r = L >> 4, c = L & 15;
      ra[s] = *(const uint4*)(A  + (size_t)(bm + r) * KD + k0 + c * 8);
      rb[s] = *(const uint4*)(Bt + (size_t)(bn + r) * KD + k0 + c * 8);
    }
    #pragma unroll
    for (int s = 0; s < 4; s++) {
      const int L = t + 256 * s;
      const int r = L >> 4, c = L & 15;
      *(uint4*)(&As[r * LDW + c * 8]) = ra[s];
      *(uint4*)(&Bs[r * LDW + c * 8]) = rb[s];
    }
    __syncthreads();

    #pragma unroll
    for (int ks = 0; ks < 4; ks++) {
      const int ko = ks * 32 + kq * 8;
      bf16x8 a0 = *(const bf16x8*)(&As[(wm + lm)      * LDW + ko]);
      bf16x8 a1 = *(const bf16x8*)(&As[(wm + 16 + lm) * LDW + ko]);
      bf16x8 b0 = *(const bf16x8*)(&Bs[(wn + lm)      * LDW + ko]);
      bf16x8 b1 = *(const bf16x8*)(&Bs[(wn + 16 + lm) * LDW + ko]);
      acc[0][0] = __builtin_amdgcn_mfma_f32_16x16x32_bf16(a0, b0, acc[0][0], 0, 0, 0);
      acc[0][1] = __builtin_amdgcn_mfma_f32_16x16x32_bf16(a0, b1, acc[0][1], 0, 0, 0);
      acc[1][0] = __builtin_amdgcn_mfma_f32_16x16x32_bf16(a1, b0, acc[1][0], 0, 0, 0);
      acc[1][1] = __builtin_amdgcn_mfma_f32_16x16x32_bf16(a1, b1, acc[1][1], 0, 0, 0);
    }
    __syncthreads();
  }

  #pragma unroll
  for (int ti = 0; ti < 2; ti++) {
    #pragma unroll
    for (int tj = 0; tj < 2; tj++) {
      const int n  = bn + wn + tj * 16 + lm;
      const int m0 = bm + wm + ti * 16 + kq * 4;
      if (EPI == 3) {
        float4 v;
        float* vp = &v.x;
        #pragma unroll
        for (int r = 0; r < 4; r++)
          vp[r] = acc[ti][tj][r] + bias[n] + b2f(RS[(size_t)(m0 + r) * 256 + n]);
        *(float4*)((float*)C0 + (size_t)n * M + m0) = v;
      } else if (EPI == 0) {
        if (n < 512) {
          #pragma unroll
          for (int r = 0; r < 4; r++)
            ((ushort*)C0)[(size_t)(m0 + r) * N + n] = f2b(acc[ti][tj][r] + bias[n]);
        } else {
          ushort4 st;
          st.x = f2b(acc[ti][tj][0] + bias[n]);
          st.y = f2b(acc[ti][tj][1] + bias[n]);
          st.z = f2b(acc[ti][tj][2] + bias[n]);
          st.w = f2b(acc[ti][tj][3] + bias[n]);
          *(ushort4*)((ushort*)C1 + (size_t)(n - 512) * 8192 + m0) = st;
        }
      } else {  // EPI 2
        #pragma unroll
        for (int r = 0; r < 4; r++) {
          const int m = m0 + r;
          float v = acc[ti][tj][r] + bias[n];
          v = 0.5f * v * (1.0f + erff(v * 0.70710678118f));
          ((ushort*)C0)[(size_t)m * N + n] = f2b(v);
        }
      }
    }
  }
}

// ---------------------------------------------------------------------------
// Fused neighborhood attention + proj. One 512-thread block (8 waves = 8
// heads) per 16-pixel tile. Phase 1 = round-13 natt per wave (barrier-free,
// h-split). Then the block's complete att rows [16][256] are parked in LDS
// (overlaying dead Plds space, 2 barriers) and proj for those 16 rows is
// computed in-block: x1b = bf16(att @ wprojT^T + b_proj + x_chw).
// Arithmetic identical to the separate proj GEMM (same bf16 att values,
// same ascending-k MFMA order).
// ---------------------------------------------------------------------------
__global__ __launch_bounds__(512, 4) void natt_proj(
    const ushort* __restrict__ qkv, const ushort* __restrict__ vT,
    const float* __restrict__ rpb, const ushort* __restrict__ wprojT,
    const float* __restrict__ b_proj, const float* __restrict__ x,
    ushort* __restrict__ x1b)
{
  __shared__ __attribute__((aligned(16))) ushort Plds[8][7][16][40];  // 71,680 B
  __shared__ float Rlds[8][176];                                      //  5,632 B
  ushort* att_lds = &Plds[0][0][0][0];   // [16][264] overlay (8448 B), post-barrier

  const int w    = threadIdx.x >> 6;      // wave = head 0..7
  const int lane = threadIdx.x & 63;
  const int l  = lane & 15;
  const int q  = lane >> 4;
  const int n  = w;
  const int tile = blockIdx.x;            // 0..511
  const int ph  = tile >> 3;
  const int pw0 = (tile & 7) << 4;
  const int p0  = ph * 128 + pw0;

  int sh = ph - 3;  sh = sh < 0 ? 0 : (sh > 57 ? 57 : sh);
  int sb = pw0 - 3; sb = sb < 0 ? 0 : sb;
  const int sba = sb & ~7;                // 16B-aligned span base; span <= 29 cols

  const float L2E = 1.44269504f;
  for (int idx = lane; idx < 169; idx += 64)
    Rlds[w][idx] = rpb[n * 169 + idx] * L2E;

  bf16x8 qf = *(const bf16x8*)(qkv + (size_t)(p0 + l) * 768 + n * 32 + q * 8);

  const float KSC = 0.17677669529663689f * 1.44269504f;  // hd^-0.5 * log2(e)
  const int relh0 = sh - ph + 6;          // 0..6
  float rsum[4] = {0.f, 0.f, 0.f, 0.f};

  #pragma unroll
  for (int h = 0; h < 2; h++) {
    f32x4 s[7] = {};
    #pragma unroll
    for (int i = 0; i < 7; i++) {
      const int rowp = (sh + i) * 128;
      int jc = sba + h * 16 + l;
      jc = jc > 127 ? 127 : jc;           // clamp addr; junk masked below
      bf16x8 kf = *(const bf16x8*)(qkv + (size_t)(rowp + jc) * 768 + 256 + n * 32 + q * 8);
      s[i] = __builtin_amdgcn_mfma_f32_16x16x32_bf16(qf, kf, s[i], 0, 0, 0);
    }
    #pragma unroll
    for (int r = 0; r < 4; r++) {
      const int pw = pw0 + q * 4 + r;
      int sw = pw - 3; sw = sw < 0 ? 0 : (sw > 121 ? 121 : sw);
      const int jc = sba + h * 16 + l;
      const bool valid = (unsigned)(jc - sw) <= 6u;
      int relw = jc - pw + 6;
      relw = relw < 0 ? 0 : (relw > 12 ? 12 : relw);
      #pragma unroll
      for (int i = 0; i < 7; i++) {
        float b = Rlds[w][(relh0 + i) * 13 + relw];
        float v = s[i][r] * KSC + b;
        v = valid ? v : -1e30f;
        float e = exp2f(v);
        rsum[r] += e;
        Plds[w][i][q * 4 + r][h * 16 + l] = f2b(e);
      }
    }
  }

  #pragma unroll
  for (int r = 0; r < 4; r++) {
    rsum[r] += __shfl_xor(rsum[r], 1);
    rsum[r] += __shfl_xor(rsum[r], 2);
    rsum[r] += __shfl_xor(rsum[r], 4);
    rsum[r] += __shfl_xor(rsum[r], 8);
  }

  f32x4 o[2] = {};
  #pragma unroll
  for (int i = 0; i < 7; i++) {
    bf16x8 pf = *(const bf16x8*)(&Plds[w][i][l][q * 8]);
    const int rowp = (sh + i) * 128;
    #pragma unroll
    for (int dh = 0; dh < 2; dh++) {
      bf16x8 vf = *(const bf16x8*)(vT + (size_t)(n * 32 + dh * 16 + l) * 8192
                                      + rowp + sba + q * 8);
      o[dh] = __builtin_amdgcn_mfma_f32_16x16x32_bf16(pf, vf, o[dh], 0, 0, 0);
    }
  }

  __syncthreads();   // all PV reads of Plds complete before overlay writes

  // park att tile [16 pixels][256 dims] in LDS (row stride 264: 4-bank shift
  // per row -> 2-way-max conflicts; 528 B rows keep b128 reads 16B-aligned)
  #pragma unroll
  for (int r = 0; r < 4; r++) {
    const float inv = 1.0f / rsum[r];
    #pragma unroll
    for (int dh = 0; dh < 2; dh++)
      att_lds[(q * 4 + r) * 264 + w * 32 + dh * 16 + l] = f2b(o[dh][r] * inv);
  }
  __syncthreads();

  // proj phase: out tile [16 m][256 n]; wave w owns n-cols w*32..w*32+31
  f32x4 pacc[2] = {};
  #pragma unroll
  for (int ks = 0; ks < 8; ks++) {
    bf16x8 a = *(const bf16x8*)(att_lds + l * 264 + ks * 32 + q * 8);
    #pragma unroll
    for (int tj = 0; tj < 2; tj++) {
      bf16x8 b = *(const bf16x8*)(wprojT + (size_t)(w * 32 + tj * 16 + l) * 256
                                         + ks * 32 + q * 8);
      pacc[tj] = __builtin_amdgcn_mfma_f32_16x16x32_bf16(a, b, pacc[tj], 0, 0, 0);
    }
  }
  #pragma unroll
  for (int tj = 0; tj < 2; tj++) {
    const int n2 = w * 32 + tj * 16 + l;
    #pragma unroll
    for (int r = 0; r < 4; r++) {
      const int m = p0 + q * 4 + r;
      float v = pacc[tj][r] + b_proj[n2] + x[(size_t)n2 * 8192 + m];
      x1b[(size_t)m * 256 + n2] = f2b(v);
    }
  }
}

// ---------------------------------------------------------------------------
extern "C" void kernel_launch(void* const* d_in, const int* in_sizes, int n_in,
                              void* d_out, int out_size, void* d_ws, size_t ws_size,
                              hipStream_t stream)
{
  const float* x      = (const float*)d_in[0];
  const float* w_qkv  = (const float*)d_in[1];
  const float* b_qkv  = (const float*)d_in[2];
  const float* rpb    = (const float*)d_in[3];
  const float* w_proj = (const float*)d_in[4];
  const float* b_proj = (const float*)d_in[5];
  const float* w_fc1  = (const float*)d_in[6];
  const float* b_fc1  = (const float*)d_in[7];
  const float* w_fc2  = (const float*)d_in[8];
  const float* b_fc2  = (const float*)d_in[9];
  float* out = (float*)d_out;

  const int M = 8192;
  char* ws = (char*)d_ws;
  ushort* xb     = (ushort*)(ws);               //  4,194,304 B
  ushort* qkv    = (ushort*)(ws + 4194304);     // 12,582,912 B (reused as h)
  ushort* x1b    = (ushort*)(ws + 16777216);    //  4,194,304 B
  ushort* wqkvT  = (ushort*)(ws + 20971520);    //    393,216 B
  ushort* wprojT = (ushort*)(ws + 21364736);    //    131,072 B
  ushort* wfc1T  = (ushort*)(ws + 21495808);    //    262,144 B
  ushort* wfc2T  = (ushort*)(ws + 21757952);    //    262,144 B
  ushort* vT     = (ushort*)(ws + 22020096);    //  4,194,304 B + 64K pad
  ushort* h   = qkv;                            // qkv dead after natt_proj

  dim3 blk(256);

  prep_kernel<<<dim3(2560), blk, 0, stream>>>(
      x, w_qkv, w_proj, w_fc1, w_fc2, xb, wqkvT, wprojT, wfc1T, wfc2T);

  // qkv = xb @ wqkvT^T + b_qkv  -> q,k rows + transposed vT
  gemm_mfma<0, 256><<<dim3(768 / 64, M / 64), blk, 0, stream>>>(
      xb, wqkvT, b_qkv, nullptr, qkv, vT, M, 768);

  // fused attention + proj: x1b = bf16(att @ wprojT^T + b_proj + x(chw))
  natt_proj<<<dim3(512), dim3(512), 0, stream>>>(
      qkv, vT, rpb, wprojT, b_proj, x, x1b);

  // h = gelu(x1b @ wfc1T^T + b_fc1) -> bf16
  gemm_mfma<2, 256><<<dim3(512 / 64, M / 64), blk, 0, stream>>>(
      x1b, wfc1T, b_fc1, nullptr, h, nullptr, M, 512);

  // out(chw) = h @ wfc2T^T + b_fc2 + b2f(x1b)
  gemm_mfma<3, 512><<<dim3(256 / 64, M / 64), blk, 0, stream>>>(
      h, wfc2T, b_fc2, x1b, out, nullptr, M, 256);
}

// Round 15
// 133.853 us; speedup vs baseline: 1.0035x; 1.0035x over previous
//
#include <hip/hip_runtime.h>

typedef unsigned short ushort;
typedef short bf16x8 __attribute__((ext_vector_type(8)));   // 8 bf16 in 4 VGPRs
typedef float f32x4 __attribute__((ext_vector_type(4)));

static __device__ __forceinline__ ushort f2b(float f) {
  unsigned u = __builtin_bit_cast(unsigned, f);
  u = (u + 0x7fffu + ((u >> 16) & 1u)) >> 16;
  return (ushort)u;
}
static __device__ __forceinline__ float b2f(ushort b) {
  return __builtin_bit_cast(float, (unsigned)b << 16);
}

// ---------------------------------------------------------------------------
// prep: LDS-tiled 32x32 transpose for all five fp32->bf16 transposes.
// ---------------------------------------------------------------------------
__global__ __launch_bounds__(256) void prep_kernel(
    const float* __restrict__ x,
    const float* __restrict__ w_qkv, const float* __restrict__ w_proj,
    const float* __restrict__ w_fc1, const float* __restrict__ w_fc2,
    ushort* __restrict__ xb, ushort* __restrict__ wqkvT,
    ushort* __restrict__ wprojT, ushort* __restrict__ wfc1T,
    ushort* __restrict__ wfc2T)
{
  __shared__ float tile[32][33];
  int t = blockIdx.x;
  const float* src; ushort* dst; int R, Nc, r0, c0;
  if (t < 2048)              { src = x;      dst = xb;     R = 256; Nc = 8192; r0 = (t >> 8) * 32; c0 = (t & 255) * 32; }
  else if ((t -= 2048) < 192){ src = w_qkv;  dst = wqkvT;  R = 256; Nc = 768;  r0 = (t / 24) * 32; c0 = (t % 24) * 32; }
  else if ((t -= 192) < 64)  { src = w_proj; dst = wprojT; R = 256; Nc = 256;  r0 = (t / 8) * 32;  c0 = (t % 8) * 32; }
  else if ((t -= 64) < 128)  { src = w_fc1;  dst = wfc1T;  R = 256; Nc = 512;  r0 = (t / 16) * 32; c0 = (t % 16) * 32; }
  else           { t -= 128;   src = w_fc2;  dst = wfc2T;  R = 512; Nc = 256;  r0 = (t / 8) * 32;  c0 = (t % 8) * 32; }

  const int tx = threadIdx.x & 31, ty = threadIdx.x >> 5;
  #pragma unroll
  for (int i = 0; i < 4; i++)
    tile[ty + i * 8][tx] = src[(size_t)(r0 + ty + i * 8) * Nc + c0 + tx];
  __syncthreads();
  #pragma unroll
  for (int i = 0; i < 4; i++)
    dst[(size_t)(c0 + ty + i * 8) * R + r0 + tx] = f2b(tile[tx][ty + i * 8]);
}

// ---------------------------------------------------------------------------
// MFMA bf16 GEMM, 64x64 tile, 4 waves, BK=128 (round-11 engine).
// EPI 0: qkv -> q,k rows to C0[m*N+n]; v (n>=512) -> C1 vT[(n-512)*8192+m]
// EPI 1: proj  -> v += b2f(RS[m*256+n]) (bf16 xb residual, coalesced along n);
//                 x1b[m*256+n] = bf16(v)
// EPI 2: fc1   -> gelu(v) -> bf16 C0[m*N+n]
// EPI 3: fc2   -> v += b2f(RS[m*256+n]); out[n*M+m]=v (f32 chw, float4)
// ---------------------------------------------------------------------------
template<int EPI, int KD>
__global__ __launch_bounds__(256) void gemm_mfma(
    const ushort* __restrict__ A, const ushort* __restrict__ Bt,
    const float* __restrict__ bias, const ushort* __restrict__ RS,
    void* __restrict__ C0, void* __restrict__ C1,
    int M, int N)
{
  constexpr int LDW = 136;                      // padded row stride (ushorts)
  __shared__ __attribute__((aligned(16))) ushort As[64 * LDW];
  __shared__ __attribute__((aligned(16))) ushort Bs[64 * LDW];

  const int bm = blockIdx.y * 64;
  const int bn = blockIdx.x * 64;
  const int t  = threadIdx.x;
  const int w    = t >> 6;
  const int lane = t & 63;
  const int wm = (w & 1) * 32;
  const int wn = (w >> 1) * 32;
  const int lm = lane & 15;
  const int kq = lane >> 4;                     // 0..3

  f32x4 acc[2][2] = {};

  #pragma unroll
  for (int k0 = 0; k0 < KD; k0 += 128) {
    uint4 ra[4], rb[4];
    #pragma unroll
    for (int s = 0; s < 4; s++) {
      const int L = t + 256 * s;
      const int r = L >> 4, c = L & 15;
      ra[s] = *(const uint4*)(A  + (size_t)(bm + r) * KD + k0 + c * 8);
      rb[s] = *(const uint4*)(Bt + (size_t)(bn + r) * KD + k0 + c * 8);
    }
    #pragma unroll
    for (int s = 0; s < 4; s++) {
      const int L = t + 256 * s;
      const int r = L >> 4, c = L & 15;
      *(uint4*)(&As[r * LDW + c * 8]) = ra[s];
      *(uint4*)(&Bs[r * LDW + c * 8]) = rb[s];
    }
    __syncthreads();

    #pragma unroll
    for (int ks = 0; ks < 4; ks++) {
      const int ko = ks * 32 + kq * 8;
      bf16x8 a0 = *(const bf16x8*)(&As[(wm + lm)      * LDW + ko]);
      bf16x8 a1 = *(const bf16x8*)(&As[(wm + 16 + lm) * LDW + ko]);
      bf16x8 b0 = *(const bf16x8*)(&Bs[(wn + lm)      * LDW + ko]);
      bf16x8 b1 = *(const bf16x8*)(&Bs[(wn + 16 + lm) * LDW + ko]);
      acc[0][0] = __builtin_amdgcn_mfma_f32_16x16x32_bf16(a0, b0, acc[0][0], 0, 0, 0);
      acc[0][1] = __builtin_amdgcn_mfma_f32_16x16x32_bf16(a0, b1, acc[0][1], 0, 0, 0);
      acc[1][0] = __builtin_amdgcn_mfma_f32_16x16x32_bf16(a1, b0, acc[1][0], 0, 0, 0);
      acc[1][1] = __builtin_amdgcn_mfma_f32_16x16x32_bf16(a1, b1, acc[1][1], 0, 0, 0);
    }
    __syncthreads();
  }

  #pragma unroll
  for (int ti = 0; ti < 2; ti++) {
    #pragma unroll
    for (int tj = 0; tj < 2; tj++) {
      const int n  = bn + wn + tj * 16 + lm;
      const int m0 = bm + wm + ti * 16 + kq * 4;
      if (EPI == 3) {
        float4 v;
        float* vp = &v.x;
        #pragma unroll
        for (int r = 0; r < 4; r++)
          vp[r] = acc[ti][tj][r] + bias[n] + b2f(RS[(size_t)(m0 + r) * 256 + n]);
        *(float4*)((float*)C0 + (size_t)n * M + m0) = v;
      } else if (EPI == 0) {
        if (n < 512) {
          #pragma unroll
          for (int r = 0; r < 4; r++)
            ((ushort*)C0)[(size_t)(m0 + r) * N + n] = f2b(acc[ti][tj][r] + bias[n]);
        } else {
          ushort4 st;
          st.x = f2b(acc[ti][tj][0] + bias[n]);
          st.y = f2b(acc[ti][tj][1] + bias[n]);
          st.z = f2b(acc[ti][tj][2] + bias[n]);
          st.w = f2b(acc[ti][tj][3] + bias[n]);
          *(ushort4*)((ushort*)C1 + (size_t)(n - 512) * 8192 + m0) = st;
        }
      } else {
        #pragma unroll
        for (int r = 0; r < 4; r++) {
          const int m = m0 + r;
          float v = acc[ti][tj][r] + bias[n];
          if (EPI == 1) {
            v += b2f(RS[(size_t)m * 256 + n]);   // bf16 xb residual, coalesced
            ((ushort*)C0)[(size_t)m * 256 + n] = f2b(v);
          } else {  // EPI 2
            v = 0.5f * v * (1.0f + erff(v * 0.70710678118f));
            ((ushort*)C0)[(size_t)m * N + n] = f2b(v);
          }
        }
      }
    }
  }
}

// ---------------------------------------------------------------------------
// MFMA neighborhood attention v3 (round-13): barrier-free, h-split,
// __launch_bounds__(256,4) pins VGPR <= 128 -> 4 blocks/CU.
// ---------------------------------------------------------------------------
__global__ __launch_bounds__(256, 4) void natt_mfma(
    const ushort* __restrict__ qkv, const ushort* __restrict__ vT,
    const float* __restrict__ rpb, ushort* __restrict__ att)
{
  __shared__ __attribute__((aligned(16))) ushort Plds[4][7][16][40];
  __shared__ float Rlds[4][176];

  const int w    = threadIdx.x >> 6;
  const int lane = threadIdx.x & 63;
  const int l  = lane & 15;
  const int q  = lane >> 4;
  const int tile = blockIdx.x;            // 0..511
  const int n    = blockIdx.y * 4 + w;    // head 0..7
  const int ph  = tile >> 3;
  const int pw0 = (tile & 7) << 4;
  const int p0  = ph * 128 + pw0;

  int sh = ph - 3;  sh = sh < 0 ? 0 : (sh > 57 ? 57 : sh);
  int sb = pw0 - 3; sb = sb < 0 ? 0 : sb;
  const int sba = sb & ~7;                // 16B-aligned span base; span <= 29 cols

  const float L2E = 1.44269504f;
  for (int idx = lane; idx < 169; idx += 64)
    Rlds[w][idx] = rpb[n * 169 + idx] * L2E;

  bf16x8 qf = *(const bf16x8*)(qkv + (size_t)(p0 + l) * 768 + n * 32 + q * 8);

  const float KSC = 0.17677669529663689f * 1.44269504f;  // hd^-0.5 * log2(e)
  const int relh0 = sh - ph + 6;          // 0..6
  float rsum[4] = {0.f, 0.f, 0.f, 0.f};

  #pragma unroll
  for (int h = 0; h < 2; h++) {
    f32x4 s[7] = {};
    #pragma unroll
    for (int i = 0; i < 7; i++) {
      const int rowp = (sh + i) * 128;
      int jc = sba + h * 16 + l;
      jc = jc > 127 ? 127 : jc;           // clamp addr; junk masked below
      bf16x8 kf = *(const bf16x8*)(qkv + (size_t)(rowp + jc) * 768 + 256 + n * 32 + q * 8);
      s[i] = __builtin_amdgcn_mfma_f32_16x16x32_bf16(qf, kf, s[i], 0, 0, 0);
    }
    #pragma unroll
    for (int r = 0; r < 4; r++) {
      const int pw = pw0 + q * 4 + r;
      int sw = pw - 3; sw = sw < 0 ? 0 : (sw > 121 ? 121 : sw);
      const int jc = sba + h * 16 + l;
      const bool valid = (unsigned)(jc - sw) <= 6u;
      int relw = jc - pw + 6;
      relw = relw < 0 ? 0 : (relw > 12 ? 12 : relw);
      #pragma unroll
      for (int i = 0; i < 7; i++) {
        float b = Rlds[w][(relh0 + i) * 13 + relw];
        float v = s[i][r] * KSC + b;
        v = valid ? v : -1e30f;
        float e = exp2f(v);
        rsum[r] += e;
        Plds[w][i][q * 4 + r][h * 16 + l] = f2b(e);
      }
    }
  }

  #pragma unroll
  for (int r = 0; r < 4; r++) {
    rsum[r] += __shfl_xor(rsum[r], 1);
    rsum[r] += __shfl_xor(rsum[r], 2);
    rsum[r] += __shfl_xor(rsum[r], 4);
    rsum[r] += __shfl_xor(rsum[r], 8);
  }

  f32x4 o[2] = {};
  #pragma unroll
  for (int i = 0; i < 7; i++) {
    bf16x8 pf = *(const bf16x8*)(&Plds[w][i][l][q * 8]);
    const int rowp = (sh + i) * 128;
    #pragma unroll
    for (int dh = 0; dh < 2; dh++) {
      bf16x8 vf = *(const bf16x8*)(vT + (size_t)(n * 32 + dh * 16 + l) * 8192
                                      + rowp + sba + q * 8);
      o[dh] = __builtin_amdgcn_mfma_f32_16x16x32_bf16(pf, vf, o[dh], 0, 0, 0);
    }
  }

  #pragma unroll
  for (int r = 0; r < 4; r++) {
    const float inv = 1.0f / rsum[r];
    #pragma unroll
    for (int dh = 0; dh < 2; dh++)
      att[(size_t)(p0 + q * 4 + r) * 256 + n * 32 + dh * 16 + l] = f2b(o[dh][r] * inv);
  }
}

// ---------------------------------------------------------------------------
extern "C" void kernel_launch(void* const* d_in, const int* in_sizes, int n_in,
                              void* d_out, int out_size, void* d_ws, size_t ws_size,
                              hipStream_t stream)
{
  const float* x      = (const float*)d_in[0];
  const float* w_qkv  = (const float*)d_in[1];
  const float* b_qkv  = (const float*)d_in[2];
  const float* rpb    = (const float*)d_in[3];
  const float* w_proj = (const float*)d_in[4];
  const float* b_proj = (const float*)d_in[5];
  const float* w_fc1  = (const float*)d_in[6];
  const float* b_fc1  = (const float*)d_in[7];
  const float* w_fc2  = (const float*)d_in[8];
  const float* b_fc2  = (const float*)d_in[9];
  float* out = (float*)d_out;

  const int M = 8192;
  char* ws = (char*)d_ws;
  ushort* xb     = (ushort*)(ws);               //  4,194,304 B
  ushort* qkv    = (ushort*)(ws + 4194304);     // 12,582,912 B (reused as h)
  ushort* x1b    = (ushort*)(ws + 16777216);    //  4,194,304 B
  ushort* wqkvT  = (ushort*)(ws + 20971520);    //    393,216 B
  ushort* wprojT = (ushort*)(ws + 21364736);    //    131,072 B
  ushort* wfc1T  = (ushort*)(ws + 21495808);    //    262,144 B
  ushort* wfc2T  = (ushort*)(ws + 21757952);    //    262,144 B
  ushort* vT     = (ushort*)(ws + 22020096);    //  4,194,304 B + 64K pad
  ushort* att    = (ushort*)(ws + 26279936);    //  4,194,304 B
  ushort* h   = qkv;                            // qkv dead after natt

  dim3 blk(256);

  prep_kernel<<<dim3(2560), blk, 0, stream>>>(
      x, w_qkv, w_proj, w_fc1, w_fc2, xb, wqkvT, wprojT, wfc1T, wfc2T);

  // qkv = xb @ wqkvT^T + b_qkv  -> q,k rows + transposed vT
  gemm_mfma<0, 256><<<dim3(768 / 64, M / 64), blk, 0, stream>>>(
      xb, wqkvT, b_qkv, nullptr, qkv, vT, M, 768);

  natt_mfma<<<dim3(512, 2), blk, 0, stream>>>(qkv, vT, rpb, att);

  // x1b = bf16(att @ wprojT^T + b_proj + xb)   (residual from bf16 xb, coalesced)
  gemm_mfma<1, 256><<<dim3(256 / 64, M / 64), blk, 0, stream>>>(
      att, wprojT, b_proj, xb, x1b, nullptr, M, 256);

  // h = gelu(x1b @ wfc1T^T + b_fc1) -> bf16
  gemm_mfma<2, 256><<<dim3(512 / 64, M / 64), blk, 0, stream>>>(
      x1b, wfc1T, b_fc1, nullptr, h, nullptr, M, 512);

  // out(chw) = h @ wfc2T^T + b_fc2 + b2f(x1b)
  gemm_mfma<3, 512><<<dim3(256 / 64, M / 64), blk, 0, stream>>>(
      h, wfc2T, b_fc2, x1b, out, nullptr, M, 256);
}

// Round 16
// 133.067 us; speedup vs baseline: 1.0094x; 1.0059x over previous
//
#include <hip/hip_runtime.h>

typedef unsigned short ushort;
typedef short bf16x8 __attribute__((ext_vector_type(8)));   // 8 bf16 in 4 VGPRs
typedef float f32x4 __attribute__((ext_vector_type(4)));

static __device__ __forceinline__ ushort f2b(float f) {
  unsigned u = __builtin_bit_cast(unsigned, f);
  u = (u + 0x7fffu + ((u >> 16) & 1u)) >> 16;
  return (ushort)u;
}
static __device__ __forceinline__ float b2f(ushort b) {
  return __builtin_bit_cast(float, (unsigned)b << 16);
}

// ---------------------------------------------------------------------------
// prep: LDS-tiled 32x32 transpose for all five fp32->bf16 transposes.
// ---------------------------------------------------------------------------
__global__ __launch_bounds__(256) void prep_kernel(
    const float* __restrict__ x,
    const float* __restrict__ w_qkv, const float* __restrict__ w_proj,
    const float* __restrict__ w_fc1, const float* __restrict__ w_fc2,
    ushort* __restrict__ xb, ushort* __restrict__ wqkvT,
    ushort* __restrict__ wprojT, ushort* __restrict__ wfc1T,
    ushort* __restrict__ wfc2T)
{
  __shared__ float tile[32][33];
  int t = blockIdx.x;
  const float* src; ushort* dst; int R, Nc, r0, c0;
  if (t < 2048)              { src = x;      dst = xb;     R = 256; Nc = 8192; r0 = (t >> 8) * 32; c0 = (t & 255) * 32; }
  else if ((t -= 2048) < 192){ src = w_qkv;  dst = wqkvT;  R = 256; Nc = 768;  r0 = (t / 24) * 32; c0 = (t % 24) * 32; }
  else if ((t -= 192) < 64)  { src = w_proj; dst = wprojT; R = 256; Nc = 256;  r0 = (t / 8) * 32;  c0 = (t % 8) * 32; }
  else if ((t -= 64) < 128)  { src = w_fc1;  dst = wfc1T;  R = 256; Nc = 512;  r0 = (t / 16) * 32; c0 = (t % 16) * 32; }
  else           { t -= 128;   src = w_fc2;  dst = wfc2T;  R = 512; Nc = 256;  r0 = (t / 8) * 32;  c0 = (t % 8) * 32; }

  const int tx = threadIdx.x & 31, ty = threadIdx.x >> 5;
  #pragma unroll
  for (int i = 0; i < 4; i++)
    tile[ty + i * 8][tx] = src[(size_t)(r0 + ty + i * 8) * Nc + c0 + tx];
  __syncthreads();
  #pragma unroll
  for (int i = 0; i < 4; i++)
    dst[(size_t)(c0 + ty + i * 8) * R + r0 + tx] = f2b(tile[tx][ty + i * 8]);
}

// ---------------------------------------------------------------------------
// MFMA bf16 GEMM, 64x64 tile, 4 waves, BK=128 (best measured engine).
// EPI 0: qkv -> q,k rows to C0[m*N+n]; v (n>=512) -> C1 vT[(n-512)*8192+m]
// EPI 1: proj  -> v += x_chw[n*M+m] (fp32 R); x1b[m*256+n] = bf16(v)
// EPI 2: fc1   -> gelu(v) -> bf16 C0[m*N+n]
// EPI 3: fc2   -> v += b2f(RS[m*256+n]); out[n*M+m]=v (f32 chw, float4)
// ---------------------------------------------------------------------------
template<int EPI, int KD>
__global__ __launch_bounds__(256) void gemm_mfma(
    const ushort* __restrict__ A, const ushort* __restrict__ Bt,
    const float* __restrict__ bias, const float* __restrict__ R,
    const ushort* __restrict__ RS,
    void* __restrict__ C0, void* __restrict__ C1,
    int M, int N)
{
  constexpr int LDW = 136;                      // padded row stride (ushorts)
  __shared__ __attribute__((aligned(16))) ushort As[64 * LDW];
  __shared__ __attribute__((aligned(16))) ushort Bs[64 * LDW];

  const int bm = blockIdx.y * 64;
  const int bn = blockIdx.x * 64;
  const int t  = threadIdx.x;
  const int w    = t >> 6;
  const int lane = t & 63;
  const int wm = (w & 1) * 32;
  const int wn = (w >> 1) * 32;
  const int lm = lane & 15;
  const int kq = lane >> 4;                     // 0..3

  f32x4 acc[2][2] = {};

  #pragma unroll
  for (int k0 = 0; k0 < KD; k0 += 128) {
    uint4 ra[4], rb[4];
    #pragma unroll
    for (int s = 0; s < 4; s++) {
      const int L = t + 256 * s;
      const int r = L >> 4, c = L & 15;
      ra[s] = *(const uint4*)(A  + (size_t)(bm + r) * KD + k0 + c * 8);
      rb[s] = *(const uint4*)(Bt + (size_t)(bn + r) * KD + k0 + c * 8);
    }
    #pragma unroll
    for (int s = 0; s < 4; s++) {
      const int L = t + 256 * s;
      const int r = L >> 4, c = L & 15;
      *(uint4*)(&As[r * LDW + c * 8]) = ra[s];
      *(uint4*)(&Bs[r * LDW + c * 8]) = rb[s];
    }
    __syncthreads();

    #pragma unroll
    for (int ks = 0; ks < 4; ks++) {
      const int ko = ks * 32 + kq * 8;
      bf16x8 a0 = *(const bf16x8*)(&As[(wm + lm)      * LDW + ko]);
      bf16x8 a1 = *(const bf16x8*)(&As[(wm + 16 + lm) * LDW + ko]);
      bf16x8 b0 = *(const bf16x8*)(&Bs[(wn + lm)      * LDW + ko]);
      bf16x8 b1 = *(const bf16x8*)(&Bs[(wn + 16 + lm) * LDW + ko]);
      acc[0][0] = __builtin_amdgcn_mfma_f32_16x16x32_bf16(a0, b0, acc[0][0], 0, 0, 0);
      acc[0][1] = __builtin_amdgcn_mfma_f32_16x16x32_bf16(a0, b1, acc[0][1], 0, 0, 0);
      acc[1][0] = __builtin_amdgcn_mfma_f32_16x16x32_bf16(a1, b0, acc[1][0], 0, 0, 0);
      acc[1][1] = __builtin_amdgcn_mfma_f32_16x16x32_bf16(a1, b1, acc[1][1], 0, 0, 0);
    }
    __syncthreads();
  }

  #pragma unroll
  for (int ti = 0; ti < 2; ti++) {
    #pragma unroll
    for (int tj = 0; tj < 2; tj++) {
      const int n  = bn + wn + tj * 16 + lm;
      const int m0 = bm + wm + ti * 16 + kq * 4;
      if (EPI == 3) {
        float4 v;
        float* vp = &v.x;
        #pragma unroll
        for (int r = 0; r < 4; r++)
          vp[r] = acc[ti][tj][r] + bias[n] + b2f(RS[(size_t)(m0 + r) * 256 + n]);
        *(float4*)((float*)C0 + (size_t)n * M + m0) = v;
      } else if (EPI == 0) {
        if (n < 512) {
          #pragma unroll
          for (int r = 0; r < 4; r++)
            ((ushort*)C0)[(size_t)(m0 + r) * N + n] = f2b(acc[ti][tj][r] + bias[n]);
        } else {
          ushort4 st;
          st.x = f2b(acc[ti][tj][0] + bias[n]);
          st.y = f2b(acc[ti][tj][1] + bias[n]);
          st.z = f2b(acc[ti][tj][2] + bias[n]);
          st.w = f2b(acc[ti][tj][3] + bias[n]);
          *(ushort4*)((ushort*)C1 + (size_t)(n - 512) * 8192 + m0) = st;
        }
      } else {
        #pragma unroll
        for (int r = 0; r < 4; r++) {
          const int m = m0 + r;
          float v = acc[ti][tj][r] + bias[n];
          if (EPI == 1) {
            v += R[(size_t)n * M + m];
            ((ushort*)C0)[(size_t)m * 256 + n] = f2b(v);
          } else {  // EPI 2
            v = 0.5f * v * (1.0f + erff(v * 0.70710678118f));
            ((ushort*)C0)[(size_t)m * N + n] = f2b(v);
          }
        }
      }
    }
  }
}

// ---------------------------------------------------------------------------
// MFMA neighborhood attention v3: barrier-free, h-split to halve score
// register pressure; __launch_bounds__(256,4) pins VGPR <= 128 -> 4 blocks/CU.
// ---------------------------------------------------------------------------
__global__ __launch_bounds__(256, 4) void natt_mfma(
    const ushort* __restrict__ qkv, const ushort* __restrict__ vT,
    const float* __restrict__ rpb, ushort* __restrict__ att)
{
  __shared__ __attribute__((aligned(16))) ushort Plds[4][7][16][40];
  __shared__ float Rlds[4][176];

  const int w    = threadIdx.x >> 6;
  const int lane = threadIdx.x & 63;
  const int l  = lane & 15;
  const int q  = lane >> 4;
  const int tile = blockIdx.x;            // 0..511
  const int n    = blockIdx.y * 4 + w;    // head 0..7
  const int ph  = tile >> 3;
  const int pw0 = (tile & 7) << 4;
  const int p0  = ph * 128 + pw0;

  int sh = ph - 3;  sh = sh < 0 ? 0 : (sh > 57 ? 57 : sh);
  int sb = pw0 - 3; sb = sb < 0 ? 0 : sb;
  const int sba = sb & ~7;                // 16B-aligned span base; span <= 29 cols

  const float L2E = 1.44269504f;
  for (int idx = lane; idx < 169; idx += 64)
    Rlds[w][idx] = rpb[n * 169 + idx] * L2E;

  bf16x8 qf = *(const bf16x8*)(qkv + (size_t)(p0 + l) * 768 + n * 32 + q * 8);

  const float KSC = 0.17677669529663689f * 1.44269504f;  // hd^-0.5 * log2(e)
  const int relh0 = sh - ph + 6;          // 0..6
  float rsum[4] = {0.f, 0.f, 0.f, 0.f};

  #pragma unroll
  for (int h = 0; h < 2; h++) {
    f32x4 s[7] = {};
    #pragma unroll
    for (int i = 0; i < 7; i++) {
      const int rowp = (sh + i) * 128;
      int jc = sba + h * 16 + l;
      jc = jc > 127 ? 127 : jc;           // clamp addr; junk masked below
      bf16x8 kf = *(const bf16x8*)(qkv + (size_t)(rowp + jc) * 768 + 256 + n * 32 + q * 8);
      s[i] = __builtin_amdgcn_mfma_f32_16x16x32_bf16(qf, kf, s[i], 0, 0, 0);
    }
    #pragma unroll
    for (int r = 0; r < 4; r++) {
      const int pw = pw0 + q * 4 + r;
      int sw = pw - 3; sw = sw < 0 ? 0 : (sw > 121 ? 121 : sw);
      const int jc = sba + h * 16 + l;
      const bool valid = (unsigned)(jc - sw) <= 6u;
      int relw = jc - pw + 6;
      relw = relw < 0 ? 0 : (relw > 12 ? 12 : relw);
      #pragma unroll
      for (int i = 0; i < 7; i++) {
        float b = Rlds[w][(relh0 + i) * 13 + relw];
        float v = s[i][r] * KSC + b;
        v = valid ? v : -1e30f;
        float e = exp2f(v);
        rsum[r] += e;
        Plds[w][i][q * 4 + r][h * 16 + l] = f2b(e);
      }
    }
  }

  #pragma unroll
  for (int r = 0; r < 4; r++) {
    rsum[r] += __shfl_xor(rsum[r], 1);
    rsum[r] += __shfl_xor(rsum[r], 2);
    rsum[r] += __shfl_xor(rsum[r], 4);
    rsum[r] += __shfl_xor(rsum[r], 8);
  }

  f32x4 o[2] = {};
  #pragma unroll
  for (int i = 0; i < 7; i++) {
    bf16x8 pf = *(const bf16x8*)(&Plds[w][i][l][q * 8]);
    const int rowp = (sh + i) * 128;
    #pragma unroll
    for (int dh = 0; dh < 2; dh++) {
      bf16x8 vf = *(const bf16x8*)(vT + (size_t)(n * 32 + dh * 16 + l) * 8192
                                      + rowp + sba + q * 8);
      o[dh] = __builtin_amdgcn_mfma_f32_16x16x32_bf16(pf, vf, o[dh], 0, 0, 0);
    }
  }

  #pragma unroll
  for (int r = 0; r < 4; r++) {
    const float inv = 1.0f / rsum[r];
    #pragma unroll
    for (int dh = 0; dh < 2; dh++)
      att[(size_t)(p0 + q * 4 + r) * 256 + n * 32 + dh * 16 + l] = f2b(o[dh][r] * inv);
  }
}

// ---------------------------------------------------------------------------
extern "C" void kernel_launch(void* const* d_in, const int* in_sizes, int n_in,
                              void* d_out, int out_size, void* d_ws, size_t ws_size,
                              hipStream_t stream)
{
  const float* x      = (const float*)d_in[0];
  const float* w_qkv  = (const float*)d_in[1];
  const float* b_qkv  = (const float*)d_in[2];
  const float* rpb    = (const float*)d_in[3];
  const float* w_proj = (const float*)d_in[4];
  const float* b_proj = (const float*)d_in[5];
  const float* w_fc1  = (const float*)d_in[6];
  const float* b_fc1  = (const float*)d_in[7];
  const float* w_fc2  = (const float*)d_in[8];
  const float* b_fc2  = (const float*)d_in[9];
  float* out = (float*)d_out;

  const int M = 8192;
  char* ws = (char*)d_ws;
  ushort* xb     = (ushort*)(ws);               //  4,194,304 B (reused as att)
  ushort* qkv    = (ushort*)(ws + 4194304);     // 12,582,912 B (reused as h)
  ushort* x1b    = (ushort*)(ws + 16777216);    //  4,194,304 B
  ushort* wqkvT  = (ushort*)(ws + 20971520);    //    393,216 B
  ushort* wprojT = (ushort*)(ws + 21364736);    //    131,072 B
  ushort* wfc1T  = (ushort*)(ws + 21495808);    //    262,144 B
  ushort* wfc2T  = (ushort*)(ws + 21757952);    //    262,144 B
  ushort* vT     = (ushort*)(ws + 22020096);    //  4,194,304 B + 64K pad
  ushort* att = xb;                             // xb dead after qkv GEMM
  ushort* h   = qkv;                            // qkv dead after natt

  dim3 blk(256);

  prep_kernel<<<dim3(2560), blk, 0, stream>>>(
      x, w_qkv, w_proj, w_fc1, w_fc2, xb, wqkvT, wprojT, wfc1T, wfc2T);

  // qkv = xb @ wqkvT^T + b_qkv  -> q,k rows + transposed vT
  gemm_mfma<0, 256><<<dim3(768 / 64, M / 64), blk, 0, stream>>>(
      xb, wqkvT, b_qkv, nullptr, nullptr, qkv, vT, M, 768);

  natt_mfma<<<dim3(512, 2), blk, 0, stream>>>(qkv, vT, rpb, att);

  // x1b = bf16(att @ wprojT^T + b_proj + x(chw))
  gemm_mfma<1, 256><<<dim3(256 / 64, M / 64), blk, 0, stream>>>(
      att, wprojT, b_proj, x, nullptr, x1b, nullptr, M, 256);

  // h = gelu(x1b @ wfc1T^T + b_fc1) -> bf16
  gemm_mfma<2, 256><<<dim3(512 / 64, M / 64), blk, 0, stream>>>(
      x1b, wfc1T, b_fc1, nullptr, nullptr, h, nullptr, M, 512);

  // out(chw) = h @ wfc2T^T + b_fc2 + b2f(x1b)
  gemm_mfma<3, 512><<<dim3(256 / 64, M / 64), blk, 0, stream>>>(
      h, wfc2T, b_fc2, nullptr, x1b, out, nullptr, M, 256);
}